// Round 5
// baseline (88.345 us; speedup 1.0000x reference)
//
#include <hip/hip_runtime.h>

#define NE 19
#define CIN 64
#define PG 4
#define ROWS (NE*PG)      // 76 rows per block
#define MTILES 5          // ceil(76/16)
#define NTHREADS 256
#define STRIDE 256        // bytes per LDS row: 128 bf16 (mixed 0-63, raw 64-127) or 64 f32 (bounce)

typedef float f32x4 __attribute__((ext_vector_type(4)));
typedef unsigned short u16x4 __attribute__((ext_vector_type(4)));
typedef unsigned short u16x8 __attribute__((ext_vector_type(8)));
typedef __bf16 bf16x8 __attribute__((ext_vector_type(8)));

__device__ __forceinline__ unsigned short f2bf(float f) {
  unsigned u = __builtin_bit_cast(unsigned, f);
  return (unsigned short)((u + 0x7FFFu + ((u >> 16) & 1u)) >> 16);
}
__device__ __forceinline__ float bf2f(unsigned short h) {
  return __builtin_bit_cast(float, (unsigned)h << 16);
}
__device__ __forceinline__ int swz(int row, int byteoff) {
  return row * STRIDE + (byteoff ^ ((row & 7) << 4));
}

__global__ __launch_bounds__(NTHREADS, 5) void gconv_kernel(
    const float* __restrict__ x, const float* __restrict__ ew,
    const float* __restrict__ Wrel, const float* __restrict__ Wroot,
    const float* __restrict__ bias, float* __restrict__ out)
{
  __shared__ __align__(16) unsigned char xc[ROWS * STRIDE];  // 19456 B
  __shared__ __align__(16) float Ap[NE][20];                 // 1520 B, col 19 zero-padded

  const int t = threadIdx.x;
  const int lane = t & 63;
  const int wv = t >> 6;
  const int row0 = blockIdx.x * ROWS;
  const float* xg = x + (long long)row0 * CIN;

  // Phase 0: A[i][j] = softplus(ew[j*19+i]), padded to 20 cols (col 19 = 0)
  for (int e = t; e < NE * 20; e += NTHREADS) {
    int i = e / 20, j = e % 20;
    float v = 0.0f;
    if (j < NE) {
      float z = ew[j * NE + i];
      v = fmaxf(z, 0.0f) + log1pf(expf(-fabsf(z)));
    }
    Ap[i][j] = v;
  }

  // Phase A: stage raw x -> xc bytes [128,256) as bf16, coalesced
  #pragma unroll
  for (int p = 0; p < 5; ++p) {
    int q = p * NTHREADS + t;
    if (q < ROWS * 16) {
      int r = q >> 4, c = q & 15;
      f32x4 v = *(const f32x4*)(xg + q * 4);
      u16x4 h;
      h[0]=f2bf(v[0]); h[1]=f2bf(v[1]); h[2]=f2bf(v[2]); h[3]=f2bf(v[3]);
      *(u16x4*)(&xc[swz(r, 128 + c * 8)]) = h;
    }
  }
  __syncthreads();   // bar1: raw x + Ap visible

  // Phase B: mix -> xc bytes [0,128). Thread = (graph g=t>>6, channel c=t&63).
  // x[j] held in regs (19 ds_read_u16); A read as b128 row chunks (broadcast).
  {
    const int g = t >> 6, c = t & 63;
    const int rb = g * NE;
    float xr[20];
    #pragma unroll
    for (int j = 0; j < NE; ++j)
      xr[j] = bf2f(*(const unsigned short*)(&xc[swz(rb + j, 128 + 2 * c)]));
    xr[19] = 0.f;
    float acc[NE];
    #pragma unroll
    for (int i = 0; i < NE; ++i) acc[i] = 0.f;
    #pragma unroll 1
    for (int jc = 0; jc < 5; ++jc) {
      #pragma unroll
      for (int i = 0; i < NE; ++i) {
        f32x4 a4 = *(const f32x4*)(&Ap[i][jc * 4]);
        #pragma unroll
        for (int k = 0; k < 4; ++k)
          acc[i] = fmaf(a4[k], xr[jc * 4 + k], acc[i]);
      }
    }
    #pragma unroll
    for (int i = 0; i < NE; ++i)
      *(unsigned short*)(&xc[swz(rb + i, 2 * c)]) = f2bf(acc[i]);
  }
  __syncthreads();   // bar2: mixed cols visible

  // B fragments (block-uniform, L2-hot). Wc[k][n]: k<64 -> Wrel[n][k] (mixed
  // channels), k>=64 -> Wroot[n][k-64] (raw channels).
  u16x8 bfrag[4][4];
  float biasv[4];
  {
    const int jl = lane & 15;
    const int k0 = (lane >> 4) * 8;
    #pragma unroll
    for (int nt = 0; nt < 4; ++nt) biasv[nt] = bias[nt * 16 + jl];
    #pragma unroll
    for (int kt = 0; kt < 4; ++kt) {
      const float* Wsrc = (kt < 2) ? Wrel : Wroot;
      const float* p = Wsrc + ((kt & 1) * 32 + k0);
      #pragma unroll
      for (int nt = 0; nt < 4; ++nt) {
        const float* q = p + (nt * 16 + jl) * CIN;
        f32x4 a = *(const f32x4*)q;
        f32x4 b = *(const f32x4*)(q + 4);
        u16x8 h;
        h[0]=f2bf(a[0]); h[1]=f2bf(a[1]); h[2]=f2bf(a[2]); h[3]=f2bf(a[3]);
        h[4]=f2bf(b[0]); h[5]=f2bf(b[1]); h[6]=f2bf(b[2]); h[7]=f2bf(b[3]);
        bfrag[kt][nt] = h;
      }
    }
  }

  // GEMM: XC[76x128] @ Wc[128x64] -> f32 bounce back into xc (full 256B rows).
  // Waves own disjoint row-tiles; same-wave LDS ops are in-order -> race-free.
  const int lr = lane & 15;
  const int hg = lane >> 4;
  for (int mt = wv; mt < MTILES; mt += 4) {
    const int r0 = mt * 16;
    int rr = r0 + lr; if (rr >= ROWS) rr = ROWS - 1;   // dup row; discarded on write
    u16x8 af[4];
    #pragma unroll
    for (int kt = 0; kt < 4; ++kt)
      af[kt] = *(const u16x8*)(&xc[swz(rr, kt * 64 + hg * 16)]);
    f32x4 acc[4];
    #pragma unroll
    for (int nt = 0; nt < 4; ++nt) { acc[nt][0]=0.f; acc[nt][1]=0.f; acc[nt][2]=0.f; acc[nt][3]=0.f; }
    #pragma unroll
    for (int kt = 0; kt < 4; ++kt)
      #pragma unroll
      for (int nt = 0; nt < 4; ++nt)
        acc[nt] = __builtin_amdgcn_mfma_f32_16x16x32_bf16(
            __builtin_bit_cast(bf16x8, af[kt]),
            __builtin_bit_cast(bf16x8, bfrag[kt][nt]), acc[nt], 0, 0, 0);
    // D: col = nt*16+lr, row = r0+hg*4+b -> f32 at byte (col*4)^swz
    #pragma unroll
    for (int nt = 0; nt < 4; ++nt)
      #pragma unroll
      for (int b = 0; b < 4; ++b) {
        int row = r0 + hg * 4 + b;
        if (row < ROWS)
          *(float*)(&xc[swz(row, (nt * 16 + lr) * 4)]) = acc[nt][b] + biasv[nt];
      }
  }
  __syncthreads();   // bar3: bounce complete

  // Epilogue: coalesced f32x4 stores (1 KB contiguous per wave instruction)
  #pragma unroll
  for (int p = 0; p < 5; ++p) {
    int q = p * NTHREADS + t;
    if (q < ROWS * 16) {
      int r = q >> 4, c = q & 15;
      f32x4 v = *(const f32x4*)(&xc[swz(r, c * 16)]);
      *(f32x4*)(out + ((long long)row0 + r) * CIN + c * 4) = v;
    }
  }
}

extern "C" void kernel_launch(void* const* d_in, const int* in_sizes, int n_in,
                              void* d_out, int out_size, void* d_ws, size_t ws_size,
                              hipStream_t stream) {
  const float* x    = (const float*)d_in[0];
  const float* ew   = (const float*)d_in[1];
  const float* Wrel = (const float*)d_in[2];
  const float* Wroot= (const float*)d_in[3];
  const float* bias = (const float*)d_in[4];
  float* out = (float*)d_out;
  const int ngraphs = (in_sizes[0] / CIN) / NE;   // 8192
  const int nblocks = ngraphs / PG;               // 2048
  gconv_kernel<<<nblocks, NTHREADS, 0, stream>>>(x, ew, Wrel, Wroot, bias, out);
}

// Round 6
// 47.902 us; speedup vs baseline: 1.8443x; 1.8443x over previous
//
#include <hip/hip_runtime.h>

#define NE 19
#define CIN 64
#define W 2                    // graphs per wave
#define WAVES 4
#define PG (W*WAVES)           // 8 graphs per block
#define WROWS (W*NE)           // 38 rows per wave slice
#define NTHREADS 256
#define STRIDE 256             // bytes per LDS row: 128 bf16 (mixed 0-63 | raw 64-127) or 64 f32 (bounce)

typedef float f32x4 __attribute__((ext_vector_type(4)));
typedef unsigned short u16x8 __attribute__((ext_vector_type(8)));
typedef __bf16 bf16x8 __attribute__((ext_vector_type(8)));

__device__ __forceinline__ unsigned short f2bf(float f) {
  unsigned u = __builtin_bit_cast(unsigned, f);
  return (unsigned short)((u + 0x7FFFu + ((u >> 16) & 1u)) >> 16);
}
__device__ __forceinline__ int swz(int row, int byteoff) {
  return row * STRIDE + (byteoff ^ ((row & 7) << 4));
}

// NO __syncthreads in this kernel: each wave's LDS slice is private, and
// same-wave ds_write -> ds_read ordering is guaranteed by compiler waitcnts.
__global__ __launch_bounds__(NTHREADS, 4) void gconv_kernel(
    const float* __restrict__ x, const float* __restrict__ ew,
    const float* __restrict__ Wrel, const float* __restrict__ Wroot,
    const float* __restrict__ bias, float* __restrict__ out)
{
  __shared__ __align__(16) unsigned char xc[WAVES * WROWS * STRIDE];  // 38912 B -> 4 blocks/CU

  const int t = threadIdx.x;
  const int lane = t & 63;
  const int wv = t >> 6;
  const int gw0 = blockIdx.x * PG + wv * W;   // first graph owned by this wave
  const int lbase = wv * WROWS;               // wave's private LDS row base

  // A = softplus(edge_weights) in 6 per-lane VGPRs: areg[r] lane l = sp(ew[r*64+l]).
  // Mix fetches A[i][j] = sp(ew[j*19+i]) via compile-time v_readlane.
  float areg[6];
  #pragma unroll
  for (int r = 0; r < 6; ++r) {
    int e = r * 64 + lane;
    float z = (e < NE * NE) ? ew[e] : 0.0f;
    areg[r] = fmaxf(z, 0.0f) + log1pf(expf(-fabsf(z)));
  }

  // Per graph: coalesced column loads (lane = channel), write raw bf16,
  // VALU mix, write mixed bf16. All into the wave-private slice.
  #pragma unroll
  for (int g = 0; g < W; ++g) {
    const float* xp = x + (long long)(gw0 + g) * NE * CIN + lane;
    float xv[NE];
    #pragma unroll
    for (int j = 0; j < NE; ++j) xv[j] = xp[j * CIN];   // 256B coalesced, L3-hot
    #pragma unroll
    for (int j = 0; j < NE; ++j)
      *(unsigned short*)(&xc[swz(lbase + g * NE + j, 128 + 2 * lane)]) = f2bf(xv[j]);
    float acc[NE];
    #pragma unroll
    for (int i = 0; i < NE; ++i) acc[i] = 0.0f;
    #pragma unroll
    for (int j = 0; j < NE; ++j) {
      #pragma unroll
      for (int i = 0; i < NE; ++i) {
        const int e = j * NE + i;   // compile-time
        float a = __builtin_bit_cast(float,
            __builtin_amdgcn_readlane(__builtin_bit_cast(int, areg[e >> 6]), e & 63));
        acc[i] = fmaf(a, xv[j], acc[i]);
      }
    }
    #pragma unroll
    for (int i = 0; i < NE; ++i)
      *(unsigned short*)(&xc[swz(lbase + g * NE + i, 2 * lane)]) = f2bf(acc[i]);
  }

  // B fragments (loaded after mix to keep VGPR peak < 128). Wc[k][n]:
  // k<64 -> Wrel[n][k] (mixed half), k>=64 -> Wroot[n][k-64] (raw half).
  u16x8 bfrag[4][4];
  float biasv[4];
  {
    const int jl = lane & 15;
    const int k0 = (lane >> 4) * 8;
    #pragma unroll
    for (int nt = 0; nt < 4; ++nt) biasv[nt] = bias[nt * 16 + jl];
    #pragma unroll
    for (int kt = 0; kt < 4; ++kt) {
      const float* Wsrc = (kt < 2) ? Wrel : Wroot;
      const float* p = Wsrc + ((kt & 1) * 32 + k0);
      #pragma unroll
      for (int nt = 0; nt < 4; ++nt) {
        const float* q = p + (nt * 16 + jl) * CIN;
        f32x4 a = *(const f32x4*)q;
        f32x4 b = *(const f32x4*)(q + 4);
        u16x8 h;
        h[0]=f2bf(a[0]); h[1]=f2bf(a[1]); h[2]=f2bf(a[2]); h[3]=f2bf(a[3]);
        h[4]=f2bf(b[0]); h[5]=f2bf(b[1]); h[6]=f2bf(b[2]); h[7]=f2bf(b[3]);
        bfrag[kt][nt] = h;
      }
    }
  }

  // GEMM over the wave's 38 rows: 3 m-tiles of 16 (tile 2 has 10 dup rows,
  // discarded on write). D bounces back f32 into the same slice rows; the
  // tile's A-read precedes its D-write in program order -> race-free.
  const int lr = lane & 15;
  const int hg = lane >> 4;
  #pragma unroll
  for (int mt = 0; mt < 3; ++mt) {
    int rr = mt * 16 + lr; if (rr >= WROWS) rr = WROWS - 1;
    u16x8 af[4];
    #pragma unroll
    for (int kt = 0; kt < 4; ++kt)
      af[kt] = *(const u16x8*)(&xc[swz(lbase + rr, kt * 64 + hg * 16)]);
    f32x4 acc[4];
    #pragma unroll
    for (int nt = 0; nt < 4; ++nt) { acc[nt][0]=0.f; acc[nt][1]=0.f; acc[nt][2]=0.f; acc[nt][3]=0.f; }
    #pragma unroll
    for (int kt = 0; kt < 4; ++kt)
      #pragma unroll
      for (int nt = 0; nt < 4; ++nt)
        acc[nt] = __builtin_amdgcn_mfma_f32_16x16x32_bf16(
            __builtin_bit_cast(bf16x8, af[kt]),
            __builtin_bit_cast(bf16x8, bfrag[kt][nt]), acc[nt], 0, 0, 0);
    // D: col = nt*16+lr, row = mt*16 + hg*4 + b
    #pragma unroll
    for (int nt = 0; nt < 4; ++nt)
      #pragma unroll
      for (int b = 0; b < 4; ++b) {
        int row = mt * 16 + hg * 4 + b;
        if (row < WROWS)
          *(float*)(&xc[swz(lbase + row, (nt * 16 + lr) * 4)]) = acc[nt][b] + biasv[nt];
      }
  }

  // Epilogue: wave-private slice -> global, 1KB contiguous per wave instruction.
  const long long orow0 = (long long)gw0 * NE;
  #pragma unroll
  for (int p = 0; p < 10; ++p) {
    int q = p * 64 + lane;
    if (q < WROWS * 16) {
      int r = q >> 4, c = q & 15;
      f32x4 v = *(const f32x4*)(&xc[swz(lbase + r, c * 16)]);
      *(f32x4*)(out + (orow0 + r) * CIN + c * 4) = v;
    }
  }
}

extern "C" void kernel_launch(void* const* d_in, const int* in_sizes, int n_in,
                              void* d_out, int out_size, void* d_ws, size_t ws_size,
                              hipStream_t stream) {
  const float* x    = (const float*)d_in[0];
  const float* ew   = (const float*)d_in[1];
  const float* Wrel = (const float*)d_in[2];
  const float* Wroot= (const float*)d_in[3];
  const float* bias = (const float*)d_in[4];
  float* out = (float*)d_out;
  const int ngraphs = (in_sizes[0] / CIN) / NE;   // 8192
  const int nblocks = ngraphs / PG;               // 1024
  gconv_kernel<<<nblocks, NTHREADS, 0, stream>>>(x, ew, Wrel, Wroot, bias, out);
}

// Round 7
// 36.504 us; speedup vs baseline: 2.4201x; 1.3122x over previous
//
#include <hip/hip_runtime.h>

#define NE 19
#define CIN 64
#define W 2                    // graphs per wave
#define WAVES 4
#define PG (W*WAVES)           // 8 graphs per block
#define WROWS (W*NE)           // 38 rows per wave slice
#define NTHREADS 256
#define STRIDE 256             // bytes per LDS row: 128 bf16 (mixed 0-63 | raw 64-127) or 64 f32 (bounce)

typedef float f32x4 __attribute__((ext_vector_type(4)));
typedef unsigned short u16x8 __attribute__((ext_vector_type(8)));
typedef __bf16 bf16x8 __attribute__((ext_vector_type(8)));

__device__ __forceinline__ unsigned short f2bf(float f) {
  unsigned u = __builtin_bit_cast(unsigned, f);
  return (unsigned short)((u + 0x7FFFu + ((u >> 16) & 1u)) >> 16);
}
__device__ __forceinline__ int swz(int row, int byteoff) {
  return row * STRIDE + (byteoff ^ ((row & 7) << 4));
}

// One barrier total (Ap visibility at start). After it, each wave works in a
// private LDS slice; same-wave DS ops are executed in order by HW -> race-free.
__global__ __launch_bounds__(NTHREADS, 2) void gconv_kernel(
    const float* __restrict__ x, const float* __restrict__ ew,
    const float* __restrict__ Wrel, const float* __restrict__ Wroot,
    const float* __restrict__ bias, float* __restrict__ out)
{
  __shared__ __align__(16) unsigned char xc[WAVES * WROWS * STRIDE];  // 38912 B
  __shared__ __align__(16) float Ap[NE][20];                          // 1520 B, col 19 = 0

  const int t = threadIdx.x;
  const int lane = t & 63;
  const int wv = t >> 6;
  const int gw0 = blockIdx.x * PG + wv * W;
  const int lbase = wv * WROWS;

  // Ap[i][j] = softplus(ew[j*19+i]) (A transposed for b128 row reads), col 19 zero
  for (int e = t; e < NE * 20; e += NTHREADS) {
    int i = e / 20, j = e % 20;
    float v = 0.0f;
    if (j < NE) {
      float z = ew[j * NE + i];
      v = fmaxf(z, 0.0f) + log1pf(expf(-fabsf(z)));
    }
    Ap[i][j] = v;
  }
  __syncthreads();   // the only barrier

  // Load both graphs' x columns (lane = channel), 38 independent 256B loads
  const float* xp0 = x + (long long)gw0 * NE * CIN + lane;
  const float* xp1 = xp0 + NE * CIN;
  float xv0[20], xv1[20];
  #pragma unroll
  for (int j = 0; j < NE; ++j) { xv0[j] = xp0[j * CIN]; xv1[j] = xp1[j * CIN]; }
  xv0[19] = 0.f; xv1[19] = 0.f;

  // Raw bf16 -> wave slice cols 64..127
  #pragma unroll
  for (int j = 0; j < NE; ++j) {
    *(unsigned short*)(&xc[swz(lbase + j,      128 + 2 * lane)]) = f2bf(xv0[j]);
    *(unsigned short*)(&xc[swz(lbase + NE + j, 128 + 2 * lane)]) = f2bf(xv1[j]);
  }

  // Mix (both graphs share each Ap b128 broadcast): 95 ds_read_b128 + 760 fma
  float acc0[NE], acc1[NE];
  #pragma unroll
  for (int i = 0; i < NE; ++i) { acc0[i] = 0.f; acc1[i] = 0.f; }
  #pragma unroll 1
  for (int jc = 0; jc < 5; ++jc) {
    #pragma unroll
    for (int i = 0; i < NE; ++i) {
      f32x4 a4 = *(const f32x4*)(&Ap[i][jc * 4]);
      #pragma unroll
      for (int k = 0; k < 4; ++k) {
        acc0[i] = fmaf(a4[k], xv0[jc * 4 + k], acc0[i]);
        acc1[i] = fmaf(a4[k], xv1[jc * 4 + k], acc1[i]);
      }
    }
  }
  #pragma unroll
  for (int i = 0; i < NE; ++i) {
    *(unsigned short*)(&xc[swz(lbase + i,      2 * lane)]) = f2bf(acc0[i]);
    *(unsigned short*)(&xc[swz(lbase + NE + i, 2 * lane)]) = f2bf(acc1[i]);
  }

  // B fragments (block-uniform, L2-hot). Wc[k][n]: k<64 -> Wrel[n][k] (mixed),
  // k>=64 -> Wroot[n][k-64] (raw).
  u16x8 bfrag[4][4];
  float biasv[4];
  {
    const int jl = lane & 15;
    const int k0 = (lane >> 4) * 8;
    #pragma unroll
    for (int nt = 0; nt < 4; ++nt) biasv[nt] = bias[nt * 16 + jl];
    #pragma unroll
    for (int kt = 0; kt < 4; ++kt) {
      const float* Wsrc = (kt < 2) ? Wrel : Wroot;
      const float* p = Wsrc + ((kt & 1) * 32 + k0);
      #pragma unroll
      for (int nt = 0; nt < 4; ++nt) {
        const float* q = p + (nt * 16 + jl) * CIN;
        f32x4 a = *(const f32x4*)q;
        f32x4 b = *(const f32x4*)(q + 4);
        u16x8 h;
        h[0]=f2bf(a[0]); h[1]=f2bf(a[1]); h[2]=f2bf(a[2]); h[3]=f2bf(a[3]);
        h[4]=f2bf(b[0]); h[5]=f2bf(b[1]); h[6]=f2bf(b[2]); h[7]=f2bf(b[3]);
        bfrag[kt][nt] = h;
      }
    }
  }

  // GEMM over the wave's 38 rows: 3 m-tiles (tile 2 has 10 dup rows, writes
  // guarded). Tile reads precede its writes in program order; tiles only read
  // rows >= their own base -> no read of previously overwritten rows.
  const int lr = lane & 15;
  const int hg = lane >> 4;
  #pragma unroll
  for (int mt = 0; mt < 3; ++mt) {
    int rr = mt * 16 + lr; if (rr >= WROWS) rr = WROWS - 1;
    u16x8 af[4];
    #pragma unroll
    for (int kt = 0; kt < 4; ++kt)
      af[kt] = *(const u16x8*)(&xc[swz(lbase + rr, kt * 64 + hg * 16)]);
    f32x4 acc[4];
    #pragma unroll
    for (int nt = 0; nt < 4; ++nt) { acc[nt][0]=0.f; acc[nt][1]=0.f; acc[nt][2]=0.f; acc[nt][3]=0.f; }
    #pragma unroll
    for (int kt = 0; kt < 4; ++kt)
      #pragma unroll
      for (int nt = 0; nt < 4; ++nt)
        acc[nt] = __builtin_amdgcn_mfma_f32_16x16x32_bf16(
            __builtin_bit_cast(bf16x8, af[kt]),
            __builtin_bit_cast(bf16x8, bfrag[kt][nt]), acc[nt], 0, 0, 0);
    // D: col = nt*16+lr, row = mt*16 + hg*4 + b -> f32 bounce
    #pragma unroll
    for (int nt = 0; nt < 4; ++nt)
      #pragma unroll
      for (int b = 0; b < 4; ++b) {
        int row = mt * 16 + hg * 4 + b;
        if (row < WROWS)
          *(float*)(&xc[swz(lbase + row, (nt * 16 + lr) * 4)]) = acc[nt][b] + biasv[nt];
      }
  }

  // Epilogue: slice -> global, 1KB contiguous per wave-instruction
  const long long orow0 = (long long)gw0 * NE;
  #pragma unroll
  for (int p = 0; p < 10; ++p) {
    int q = p * 64 + lane;
    if (q < WROWS * 16) {
      int r = q >> 4, c = q & 15;
      f32x4 v = *(const f32x4*)(&xc[swz(lbase + r, c * 16)]);
      *(f32x4*)(out + (orow0 + r) * CIN + c * 4) = v;
    }
  }
}

extern "C" void kernel_launch(void* const* d_in, const int* in_sizes, int n_in,
                              void* d_out, int out_size, void* d_ws, size_t ws_size,
                              hipStream_t stream) {
  const float* x    = (const float*)d_in[0];
  const float* ew   = (const float*)d_in[1];
  const float* Wrel = (const float*)d_in[2];
  const float* Wroot= (const float*)d_in[3];
  const float* bias = (const float*)d_in[4];
  float* out = (float*)d_out;
  const int ngraphs = (in_sizes[0] / CIN) / NE;   // 8192
  const int nblocks = ngraphs / PG;               // 1024
  gconv_kernel<<<nblocks, NTHREADS, 0, stream>>>(x, ew, Wrel, Wroot, bias, out);
}

// Round 8
// 33.393 us; speedup vs baseline: 2.6456x; 1.0932x over previous
//
#include <hip/hip_runtime.h>

#define NE 19
#define NEDGE 361
#define CIN 64
#define STRIDE 256            // bytes per LDS row (M tile bf16 in [0,128), f32 bounce full row)
#define WS_FRAG_BYTE 1536     // ws layout: [0,361) f32 softplus(A); frags at byte 1536 (16 KB)

typedef float f32x4 __attribute__((ext_vector_type(4)));
typedef unsigned short u16x8 __attribute__((ext_vector_type(8)));
typedef __bf16 bf16x8 __attribute__((ext_vector_type(8)));

__device__ __forceinline__ unsigned short f2bf(float f) {
  unsigned u = __builtin_bit_cast(unsigned, f);
  return (unsigned short)((u + 0x7FFFu + ((u >> 16) & 1u)) >> 16);
}
__device__ __forceinline__ int swz(int row, int byteoff) {
  return row * STRIDE + (byteoff ^ ((row & 7) << 4));
}

// K1: softplus(A) + W fragments (bf16, MFMA B-frag layout) into workspace.
// frag id = ((pass*2 + kt)*4 + nt)*64 + lane; pass0 = Wroot (raw X), pass1 = Wrel (M).
__global__ void prep_kernel(const float* __restrict__ ew,
                            const float* __restrict__ Wrel,
                            const float* __restrict__ Wroot,
                            float* __restrict__ ws) {
  const int t = threadIdx.x;
  for (int e = t; e < NEDGE; e += 256) {
    float z = ew[e];
    ws[e] = fmaxf(z, 0.0f) + log1pf(expf(-fabsf(z)));
  }
  for (int fid = t; fid < 1024; fid += 256) {
    int p = fid >> 9, kt = (fid >> 8) & 1, nt = (fid >> 6) & 3, lane = fid & 63;
    const float* Wsrc = p ? Wrel : Wroot;
    const float* q = Wsrc + (nt * 16 + (lane & 15)) * CIN + kt * 32 + (lane >> 4) * 8;
    u16x8 h;
    #pragma unroll
    for (int b = 0; b < 8; ++b) h[b] = f2bf(q[b]);
    *(u16x8*)((char*)ws + WS_FRAG_BYTE + fid * 16) = h;
  }
}

// K2: one graph per wave, zero barriers, wave-private 19-row LDS slice.
// out = M@Wrel^T + X@Wroot^T + b,  M = A·X (readlane mix, A in 6 VGPRs).
__global__ __launch_bounds__(128, 2) void gconv_kernel(
    const float* __restrict__ x, const float* __restrict__ bias,
    const float* __restrict__ ws, float* __restrict__ out)
{
  __shared__ __align__(16) unsigned char xc[2 * NE * STRIDE];  // 9728 B

  const int t = threadIdx.x;
  const int lane = t & 63;
  const int wv = t >> 6;
  const int g = blockIdx.x * 2 + wv;
  const int sbase = wv * NE;
  const float* xg = x + (long long)g * NE * CIN;
  const int lr = lane & 15, hg = lane >> 4;

  // A rows in VGPRs: areg[r] lane l = softplus(ew)[r*64+l]
  float areg[6];
  #pragma unroll
  for (int r = 0; r < 6; ++r) {
    int e = r * 64 + lane;
    areg[r] = (e < NEDGE) ? ws[e] : 0.0f;
  }
  // x columns for the mix (lane = channel), 19 × 256B coalesced loads
  float xv[NE];
  #pragma unroll
  for (int j = 0; j < NE; ++j) xv[j] = xg[j * CIN + lane];

  float biasv[4];
  #pragma unroll
  for (int nt = 0; nt < 4; ++nt) biasv[nt] = bias[nt * 16 + lr];

  const u16x8* fr = (const u16x8*)((const char*)ws + WS_FRAG_BYTE);

  // ---- pass 1: X @ Wroot^T. A-frags straight from global (32B/lane contiguous).
  u16x8 bf[2][4];
  #pragma unroll
  for (int kt = 0; kt < 2; ++kt)
    #pragma unroll
    for (int nt = 0; nt < 4; ++nt)
      bf[kt][nt] = fr[(kt * 4 + nt) * 64 + lane];

  f32x4 gacc[2][4];
  #pragma unroll
  for (int mt = 0; mt < 2; ++mt)
    #pragma unroll
    for (int nt = 0; nt < 4; ++nt) { gacc[mt][nt][0]=0.f; gacc[mt][nt][1]=0.f; gacc[mt][nt][2]=0.f; gacc[mt][nt][3]=0.f; }

  #pragma unroll
  for (int mt = 0; mt < 2; ++mt) {
    int rr = mt * 16 + lr; if (rr > NE - 1) rr = NE - 1;   // dup rows, writes guarded
    const float* xr = xg + rr * CIN + hg * 8;
    u16x8 af[2];
    #pragma unroll
    for (int kt = 0; kt < 2; ++kt) {
      f32x4 a = *(const f32x4*)(xr + kt * 32);
      f32x4 b = *(const f32x4*)(xr + kt * 32 + 4);
      u16x8 h;
      h[0]=f2bf(a[0]); h[1]=f2bf(a[1]); h[2]=f2bf(a[2]); h[3]=f2bf(a[3]);
      h[4]=f2bf(b[0]); h[5]=f2bf(b[1]); h[6]=f2bf(b[2]); h[7]=f2bf(b[3]);
      af[kt] = h;
    }
    #pragma unroll
    for (int kt = 0; kt < 2; ++kt)
      #pragma unroll
      for (int nt = 0; nt < 4; ++nt)
        gacc[mt][nt] = __builtin_amdgcn_mfma_f32_16x16x32_bf16(
            __builtin_bit_cast(bf16x8, af[kt]),
            __builtin_bit_cast(bf16x8, bf[kt][nt]), gacc[mt][nt], 0, 0, 0);
  }

  // ---- mix: macc[i] = sum_j A[i][j]*xv[j]; A[i][j] = sp(ew[j*19+i]) = lane j*19+i
  float macc[NE];
  #pragma unroll
  for (int i = 0; i < NE; ++i) macc[i] = 0.0f;
  #pragma unroll
  for (int j = 0; j < NE; ++j)
    #pragma unroll
    for (int i = 0; i < NE; ++i) {
      const int e = j * NE + i;   // compile-time
      float a = __builtin_bit_cast(float,
          __builtin_amdgcn_readlane(__builtin_bit_cast(int, areg[e >> 6]), e & 63));
      macc[i] = fmaf(a, xv[j], macc[i]);
    }
  // M -> wave slice (bf16), lane = channel
  #pragma unroll
  for (int i = 0; i < NE; ++i)
    *(unsigned short*)(&xc[swz(sbase + i, 2 * lane)]) = f2bf(macc[i]);

  // ---- pass 2: M @ Wrel^T (A-frags from LDS)
  #pragma unroll
  for (int kt = 0; kt < 2; ++kt)
    #pragma unroll
    for (int nt = 0; nt < 4; ++nt)
      bf[kt][nt] = fr[(8 + kt * 4 + nt) * 64 + lane];

  #pragma unroll
  for (int mt = 0; mt < 2; ++mt) {
    int rr = mt * 16 + lr; if (rr > NE - 1) rr = NE - 1;
    u16x8 af[2];
    #pragma unroll
    for (int kt = 0; kt < 2; ++kt)
      af[kt] = *(const u16x8*)(&xc[swz(sbase + rr, kt * 64 + hg * 16)]);
    #pragma unroll
    for (int kt = 0; kt < 2; ++kt)
      #pragma unroll
      for (int nt = 0; nt < 4; ++nt)
        gacc[mt][nt] = __builtin_amdgcn_mfma_f32_16x16x32_bf16(
            __builtin_bit_cast(bf16x8, af[kt]),
            __builtin_bit_cast(bf16x8, bf[kt][nt]), gacc[mt][nt], 0, 0, 0);
  }

  // ---- bias + f32 bounce into the slice (full 256B rows)
  #pragma unroll
  for (int mt = 0; mt < 2; ++mt)
    #pragma unroll
    for (int nt = 0; nt < 4; ++nt)
      #pragma unroll
      for (int b = 0; b < 4; ++b) {
        int row = mt * 16 + hg * 4 + b;
        if (row < NE)
          *(float*)(&xc[swz(sbase + row, (nt * 16 + lr) * 4)]) = gacc[mt][nt][b] + biasv[nt];
      }

  // ---- epilogue: 1KB-contiguous f32x4 stores
  const long long orow0 = (long long)g * NE;
  #pragma unroll
  for (int p = 0; p < 5; ++p) {
    int q = p * 64 + lane;
    if (q < NE * 16) {
      int r = q >> 4, c = q & 15;
      f32x4 v = *(const f32x4*)(&xc[swz(sbase + r, c * 16)]);
      *(f32x4*)(out + (orow0 + r) * CIN + c * 4) = v;
    }
  }
}

extern "C" void kernel_launch(void* const* d_in, const int* in_sizes, int n_in,
                              void* d_out, int out_size, void* d_ws, size_t ws_size,
                              hipStream_t stream) {
  const float* x    = (const float*)d_in[0];
  const float* ew   = (const float*)d_in[1];
  const float* Wrel = (const float*)d_in[2];
  const float* Wroot= (const float*)d_in[3];
  const float* bias = (const float*)d_in[4];
  float* out = (float*)d_out;
  float* ws  = (float*)d_ws;   // needs 1536 + 16384 = 17920 bytes

  prep_kernel<<<1, 256, 0, stream>>>(ew, Wrel, Wroot, ws);

  const int ngraphs = (in_sizes[0] / CIN) / NE;   // 8192
  const int nblocks = ngraphs / 2;                // 4096 blocks, 1 graph/wave
  gconv_kernel<<<nblocks, 128, 0, stream>>>(x, bias, ws, out);
}

// Round 9
// 29.414 us; speedup vs baseline: 3.0035x; 1.1353x over previous
//
#include <hip/hip_runtime.h>

#define NE 19
#define NEDGE 361
#define CIN 64
#define Z1T_STRIDE 80          // bytes per Z1T row (32 bf16 used of 40); 80=5*16 keeps 16B align, 2-way banks
#define Z1T_BYTES (CIN * Z1T_STRIDE)   // 5120 per wave
#define OB_BYTES (NE * 256)            // 4864 per wave (swizzled 256B rows)
#define WS_AFRAG_BYTE 16384    // ws: [0,16K) Wc B-frags (0-7 Wrel, 8-15 Wroot); [16K,18K) A-mix frags

typedef float f32x4 __attribute__((ext_vector_type(4)));
typedef unsigned short u16x4 __attribute__((ext_vector_type(4)));
typedef unsigned short u16x8 __attribute__((ext_vector_type(8)));
typedef __bf16 bf16x8 __attribute__((ext_vector_type(8)));

__device__ __forceinline__ unsigned short f2bf(float f) {
  unsigned u = __builtin_bit_cast(unsigned, f);
  return (unsigned short)((u + 0x7FFFu + ((u >> 16) & 1u)) >> 16);
}
__device__ __forceinline__ int swz(int row, int byteoff) {
  return row * 256 + (byteoff ^ ((row & 7) << 4));
}

// K1: pack Wc into MFMA B-fragments and A (softplus, transposed) into MFMA
// A-fragments, all bf16, in workspace. Graph-invariant -> done once per launch.
__global__ void prep_kernel(const float* __restrict__ ew,
                            const float* __restrict__ Wrel,
                            const float* __restrict__ Wroot,
                            unsigned char* __restrict__ ws) {
  const int t = threadIdx.x;
  // Wc B-frags: fid = ((p*2+kt)*4+nt)*64+lane ; p0=Wrel, p1=Wroot
  for (int fid = t; fid < 1024; fid += 256) {
    int p = fid >> 9, kt = (fid >> 8) & 1, nt = (fid >> 6) & 3, lane = fid & 63;
    const float* Wsrc = p ? Wroot : Wrel;
    const float* q = Wsrc + (nt * 16 + (lane & 15)) * CIN + kt * 32 + (lane >> 4) * 8;
    u16x8 h;
    #pragma unroll
    for (int b = 0; b < 8; ++b) h[b] = f2bf(q[b]);
    *(u16x8*)(ws + fid * 16) = h;
  }
  // A-mix A-frags: lane holds A[mt*16+(lane&15)][k=(lane>>4)*8+b], A[i][j]=sp(ew[j*19+i])
  for (int id = t; id < 128; id += 256) {
    int mt = id >> 6, lane = id & 63;
    int row = mt * 16 + (lane & 15);
    u16x8 h;
    #pragma unroll
    for (int b = 0; b < 8; ++b) {
      int k = (lane >> 4) * 8 + b;
      float v = 0.0f;
      if (row < NE && k < NE) {
        float z = ew[k * NE + row];
        v = fmaxf(z, 0.0f) + log1pf(expf(-fabsf(z)));
      }
      h[b] = f2bf(v);
    }
    *(u16x8*)(ws + WS_AFRAG_BYTE + id * 16) = h;
  }
}

// K2: 1 graph per wave, zero barriers, all compute in MFMA.
// out = A@(X@Wrel^T) + X@Wroot^T + bias
__global__ __launch_bounds__(128, 2) void gconv_kernel(
    const float* __restrict__ x, const float* __restrict__ bias,
    const unsigned char* __restrict__ ws, float* __restrict__ out)
{
  __shared__ __align__(16) unsigned char z1t[2 * Z1T_BYTES];  // 10240 B
  __shared__ __align__(16) unsigned char ob[2 * OB_BYTES];    // 9728 B

  const int t = threadIdx.x;
  const int lane = t & 63;
  const int wv = t >> 6;
  const int g = blockIdx.x * 2 + wv;
  const float* xg = x + (long long)g * NE * CIN;
  const int lr = lane & 15, hg = lane >> 4;
  unsigned char* z1 = z1t + wv * Z1T_BYTES;
  unsigned char* obw = ob + wv * OB_BYTES;
  const u16x8* fr = (const u16x8*)ws;

  // A-mix fragments (graph-invariant, L2-hot)
  u16x8 afm[2];
  afm[0] = fr[1024 + lane];
  afm[1] = fr[1024 + 64 + lane];

  // X A-frags from global (32B/lane contiguous), both m-tiles, f32->bf16
  u16x8 af[2][2];
  #pragma unroll
  for (int mt = 0; mt < 2; ++mt) {
    int rr = mt * 16 + lr; if (rr > NE - 1) rr = NE - 1;  // dup rows, writes guarded
    const float* xr = xg + rr * CIN + hg * 8;
    #pragma unroll
    for (int kt = 0; kt < 2; ++kt) {
      f32x4 a = *(const f32x4*)(xr + kt * 32);
      f32x4 b = *(const f32x4*)(xr + kt * 32 + 4);
      u16x8 h;
      h[0]=f2bf(a[0]); h[1]=f2bf(a[1]); h[2]=f2bf(a[2]); h[3]=f2bf(a[3]);
      h[4]=f2bf(b[0]); h[5]=f2bf(b[1]); h[6]=f2bf(b[2]); h[7]=f2bf(b[3]);
      af[mt][kt] = h;
    }
  }

  float biasv[4];
  #pragma unroll
  for (int nt = 0; nt < 4; ++nt) biasv[nt] = bias[nt * 16 + lr];

  // ---- half 1: Z1 = X @ Wrel^T (16 MFMA)
  {
    u16x8 bf1[2][4];
    #pragma unroll
    for (int kt = 0; kt < 2; ++kt)
      #pragma unroll
      for (int nt = 0; nt < 4; ++nt)
        bf1[kt][nt] = fr[(kt * 4 + nt) * 64 + lane];
    f32x4 zacc[2][4];
    #pragma unroll
    for (int mt = 0; mt < 2; ++mt)
      #pragma unroll
      for (int nt = 0; nt < 4; ++nt) { zacc[mt][nt][0]=0.f; zacc[mt][nt][1]=0.f; zacc[mt][nt][2]=0.f; zacc[mt][nt][3]=0.f; }
    #pragma unroll
    for (int mt = 0; mt < 2; ++mt)
      #pragma unroll
      for (int kt = 0; kt < 2; ++kt)
        #pragma unroll
        for (int nt = 0; nt < 4; ++nt)
          zacc[mt][nt] = __builtin_amdgcn_mfma_f32_16x16x32_bf16(
              __builtin_bit_cast(bf16x8, af[mt][kt]),
              __builtin_bit_cast(bf16x8, bf1[kt][nt]), zacc[mt][nt], 0, 0, 0);

    // bounce Z1 -> Z1T[c][j] bf16 (j zero-padded to 32). D row = node j =
    // mt*16+hg*4+b, D col = c = nt*16+lr. 8 ds_write_b64, 2-way banks.
    #pragma unroll
    for (int nt = 0; nt < 4; ++nt) {
      int c = nt * 16 + lr;
      u16x4 h0;
      #pragma unroll
      for (int b = 0; b < 4; ++b) h0[b] = f2bf(zacc[0][nt][b]);
      *(u16x4*)(z1 + c * Z1T_STRIDE + hg * 8) = h0;
      u16x4 h1;
      #pragma unroll
      for (int b = 0; b < 4; ++b) {
        int j = 16 + hg * 4 + b;
        h1[b] = (j < NE) ? f2bf(zacc[1][nt][b]) : (unsigned short)0;
      }
      *(u16x4*)(z1 + c * Z1T_STRIDE + 32 + hg * 8) = h1;
    }
  }

  // ---- half 2: acc = bias + X @ Wroot^T (16 MFMA)
  f32x4 acc[2][4];
  #pragma unroll
  for (int mt = 0; mt < 2; ++mt)
    #pragma unroll
    for (int nt = 0; nt < 4; ++nt) { acc[mt][nt][0]=biasv[nt]; acc[mt][nt][1]=biasv[nt]; acc[mt][nt][2]=biasv[nt]; acc[mt][nt][3]=biasv[nt]; }
  {
    u16x8 bf2[2][4];
    #pragma unroll
    for (int kt = 0; kt < 2; ++kt)
      #pragma unroll
      for (int nt = 0; nt < 4; ++nt)
        bf2[kt][nt] = fr[(8 + kt * 4 + nt) * 64 + lane];
    #pragma unroll
    for (int mt = 0; mt < 2; ++mt)
      #pragma unroll
      for (int kt = 0; kt < 2; ++kt)
        #pragma unroll
        for (int nt = 0; nt < 4; ++nt)
          acc[mt][nt] = __builtin_amdgcn_mfma_f32_16x16x32_bf16(
              __builtin_bit_cast(bf16x8, af[mt][kt]),
              __builtin_bit_cast(bf16x8, bf2[kt][nt]), acc[mt][nt], 0, 0, 0);
  }

  // ---- mix as MFMA: acc += A @ Z1. B-frags: lane reads Z1T[nt*16+lr][hg*8..+7]
  {
    u16x8 zf[4];
    #pragma unroll
    for (int nt = 0; nt < 4; ++nt)
      zf[nt] = *(const u16x8*)(z1 + (nt * 16 + lr) * Z1T_STRIDE + hg * 16);
    #pragma unroll
    for (int mt = 0; mt < 2; ++mt)
      #pragma unroll
      for (int nt = 0; nt < 4; ++nt)
        acc[mt][nt] = __builtin_amdgcn_mfma_f32_16x16x32_bf16(
            __builtin_bit_cast(bf16x8, afm[mt]),
            __builtin_bit_cast(bf16x8, zf[nt]), acc[mt][nt], 0, 0, 0);
  }

  // ---- out bounce (swizzled 256B rows) + coalesced epilogue
  #pragma unroll
  for (int mt = 0; mt < 2; ++mt)
    #pragma unroll
    for (int nt = 0; nt < 4; ++nt)
      #pragma unroll
      for (int b = 0; b < 4; ++b) {
        int row = mt * 16 + hg * 4 + b;
        if (row < NE)
          *(float*)(&obw[swz(row, (nt * 16 + lr) * 4)]) = acc[mt][nt][b];
      }
  const long long orow0 = (long long)g * NE;
  #pragma unroll
  for (int p = 0; p < 5; ++p) {
    int q = p * 64 + lane;
    if (q < NE * 16) {
      int r = q >> 4, c = q & 15;
      f32x4 v = *(const f32x4*)(&obw[swz(r, c * 16)]);
      *(f32x4*)(out + (orow0 + r) * CIN + c * 4) = v;
    }
  }
}

extern "C" void kernel_launch(void* const* d_in, const int* in_sizes, int n_in,
                              void* d_out, int out_size, void* d_ws, size_t ws_size,
                              hipStream_t stream) {
  const float* x    = (const float*)d_in[0];
  const float* ew   = (const float*)d_in[1];
  const float* Wrel = (const float*)d_in[2];
  const float* Wroot= (const float*)d_in[3];
  const float* bias = (const float*)d_in[4];
  float* out = (float*)d_out;
  unsigned char* ws = (unsigned char*)d_ws;   // needs 16384 + 2048 = 18432 B

  prep_kernel<<<1, 256, 0, stream>>>(ew, Wrel, Wroot, ws);

  const int ngraphs = (in_sizes[0] / CIN) / NE;   // 8192
  const int nblocks = ngraphs / 2;                // 4096 blocks, 1 graph/wave
  gconv_kernel<<<nblocks, 128, 0, stream>>>(x, bias, ws, out);
}

// Round 10
// 28.559 us; speedup vs baseline: 3.0934x; 1.0299x over previous
//
#include <hip/hip_runtime.h>

#define NE 19
#define CIN 64
#define Z1T_STRIDE 80          // bytes per Z1T row (32 bf16 of 40); 16B-aligned, 2-way banks = free
#define SLICE 5120             // per-wave slice: Z1T, then reused as f32 out-bounce (4864 B)
#define WS_AFRAG 16384         // ws: [0,16K) Wc B-frags; [16K,18K) A-mix A-frags

typedef float f32x4 __attribute__((ext_vector_type(4)));
typedef unsigned short u16x4 __attribute__((ext_vector_type(4)));
typedef unsigned short u16x8 __attribute__((ext_vector_type(8)));
typedef __bf16 bf16x8 __attribute__((ext_vector_type(8)));

__device__ __forceinline__ unsigned short f2bf(float f) {
  unsigned u = __builtin_bit_cast(unsigned, f);
  return (unsigned short)((u + 0x7FFFu + ((u >> 16) & 1u)) >> 16);
}
__device__ __forceinline__ int swz(int row, int byteoff) {
  return row * 256 + (byteoff ^ ((row & 7) << 4));
}

// K1 (5 blocks): pack Wc B-frags + softplus(A) A-frags (bf16) into workspace.
// B-frag fid = ((p*2+kt)*4+nt)*64+lane, p0=Wrel p1=Wroot.
__global__ void prep_kernel(const float* __restrict__ ew,
                            const float* __restrict__ Wrel,
                            const float* __restrict__ Wroot,
                            unsigned char* __restrict__ ws) {
  const int t = threadIdx.x, bid = blockIdx.x;
  if (bid < 4) {
    int fid = bid * 256 + t;
    int p = fid >> 9, kt = (fid >> 8) & 1, nt = (fid >> 6) & 3, lane = fid & 63;
    const float* Wsrc = p ? Wroot : Wrel;
    const float* q = Wsrc + (nt * 16 + (lane & 15)) * CIN + kt * 32 + (lane >> 4) * 8;
    u16x8 h;
    #pragma unroll
    for (int b = 0; b < 8; ++b) h[b] = f2bf(q[b]);
    *(u16x8*)(ws + fid * 16) = h;
  } else if (t < 128) {
    // A-mix A-frag: lane holds A[mt*16+(lane&15)][k=(lane>>4)*8+b], A[i][j]=sp(ew[j*19+i])
    int mt = t >> 6, lane = t & 63;
    int row = mt * 16 + (lane & 15);
    u16x8 h;
    #pragma unroll
    for (int b = 0; b < 8; ++b) {
      int k = (lane >> 4) * 8 + b;
      float v = 0.0f;
      if (row < NE && k < NE) {
        float z = ew[k * NE + row];
        v = fmaxf(z, 0.0f) + log1pf(expf(-fabsf(z)));
      }
      h[b] = f2bf(v);
    }
    *(u16x8*)(ws + WS_AFRAG + t * 16) = h;
  }
}

// K2: 1 graph/wave, zero barriers, all compute in MFMA, VGPR-dieted to 64.
// out = A@(X@Wrel^T) + X@Wroot^T + bias
__global__ __launch_bounds__(128, 8) void gconv_kernel(
    const float* __restrict__ x, const float* __restrict__ bias,
    const unsigned char* __restrict__ ws, float* __restrict__ out)
{
  __shared__ __align__(16) unsigned char sl[2 * SLICE];  // 10240 B -> 16 blocks/CU

  const int t = threadIdx.x;
  const int lane = t & 63;
  const int wv = t >> 6;
  const int g = blockIdx.x * 2 + wv;
  const int lr = lane & 15, hg = lane >> 4;
  const float* xg = x + (long long)g * NE * CIN;
  unsigned char* z1 = sl + wv * SLICE;
  const u16x8* fr = (const u16x8*)ws;

  // X A-frags (single x pass, 32B/lane contiguous, f32->bf16)
  u16x8 af[2][2];
  #pragma unroll
  for (int mt = 0; mt < 2; ++mt) {
    int rr = mt * 16 + lr; if (rr > NE - 1) rr = NE - 1;  // dup rows, writes guarded
    const float* xr = xg + rr * CIN + hg * 8;
    #pragma unroll
    for (int kt = 0; kt < 2; ++kt) {
      f32x4 a = *(const f32x4*)(xr + kt * 32);
      f32x4 b = *(const f32x4*)(xr + kt * 32 + 4);
      u16x8 h;
      h[0]=f2bf(a[0]); h[1]=f2bf(a[1]); h[2]=f2bf(a[2]); h[3]=f2bf(a[3]);
      h[4]=f2bf(b[0]); h[5]=f2bf(b[1]); h[6]=f2bf(b[2]); h[7]=f2bf(b[3]);
      af[mt][kt] = h;
    }
  }

  // half 1: Z1 = X @ Wrel^T, B-frags streamed per nt (8 transient regs)
  f32x4 zacc[2][4];
  #pragma unroll
  for (int mt = 0; mt < 2; ++mt)
    #pragma unroll
    for (int nt = 0; nt < 4; ++nt) { zacc[mt][nt][0]=0.f; zacc[mt][nt][1]=0.f; zacc[mt][nt][2]=0.f; zacc[mt][nt][3]=0.f; }
  #pragma unroll
  for (int nt = 0; nt < 4; ++nt) {
    u16x8 b0 = fr[nt * 64 + lane];
    u16x8 b1 = fr[(4 + nt) * 64 + lane];
    #pragma unroll
    for (int mt = 0; mt < 2; ++mt) {
      zacc[mt][nt] = __builtin_amdgcn_mfma_f32_16x16x32_bf16(
          __builtin_bit_cast(bf16x8, af[mt][0]), __builtin_bit_cast(bf16x8, b0), zacc[mt][nt], 0, 0, 0);
      zacc[mt][nt] = __builtin_amdgcn_mfma_f32_16x16x32_bf16(
          __builtin_bit_cast(bf16x8, af[mt][1]), __builtin_bit_cast(bf16x8, b1), zacc[mt][nt], 0, 0, 0);
    }
  }

  // bounce Z1 -> Z1T[c][j] bf16 (j 19..31 zeroed). 8 ds_write_b64/lane.
  #pragma unroll
  for (int nt = 0; nt < 4; ++nt) {
    int c = nt * 16 + lr;
    u16x4 h0;
    #pragma unroll
    for (int b = 0; b < 4; ++b) h0[b] = f2bf(zacc[0][nt][b]);
    *(u16x4*)(z1 + c * Z1T_STRIDE + hg * 8) = h0;
    u16x4 h1;
    #pragma unroll
    for (int b = 0; b < 4; ++b) {
      int j = 16 + hg * 4 + b;
      h1[b] = (j < NE) ? f2bf(zacc[1][nt][b]) : (unsigned short)0;
    }
    *(u16x4*)(z1 + c * Z1T_STRIDE + 32 + hg * 8) = h1;
  }

  // half 2: acc = X @ Wroot^T (bias deferred to epilogue), streamed B-frags
  f32x4 acc[2][4];
  #pragma unroll
  for (int mt = 0; mt < 2; ++mt)
    #pragma unroll
    for (int nt = 0; nt < 4; ++nt) { acc[mt][nt][0]=0.f; acc[mt][nt][1]=0.f; acc[mt][nt][2]=0.f; acc[mt][nt][3]=0.f; }
  #pragma unroll
  for (int nt = 0; nt < 4; ++nt) {
    u16x8 b0 = fr[(8 + nt) * 64 + lane];
    u16x8 b1 = fr[(12 + nt) * 64 + lane];
    #pragma unroll
    for (int mt = 0; mt < 2; ++mt) {
      acc[mt][nt] = __builtin_amdgcn_mfma_f32_16x16x32_bf16(
          __builtin_bit_cast(bf16x8, af[mt][0]), __builtin_bit_cast(bf16x8, b0), acc[mt][nt], 0, 0, 0);
      acc[mt][nt] = __builtin_amdgcn_mfma_f32_16x16x32_bf16(
          __builtin_bit_cast(bf16x8, af[mt][1]), __builtin_bit_cast(bf16x8, b1), acc[mt][nt], 0, 0, 0);
    }
  }

  // mix as MFMA: acc += A @ Z1 (A-frags graph-invariant, L2-hot; zf streamed)
  {
    u16x8 afm0 = fr[1024 + lane];
    u16x8 afm1 = fr[1088 + lane];
    #pragma unroll
    for (int nt = 0; nt < 4; ++nt) {
      u16x8 zf = *(const u16x8*)(z1 + (nt * 16 + lr) * Z1T_STRIDE + hg * 16);
      acc[0][nt] = __builtin_amdgcn_mfma_f32_16x16x32_bf16(
          __builtin_bit_cast(bf16x8, afm0), __builtin_bit_cast(bf16x8, zf), acc[0][nt], 0, 0, 0);
      acc[1][nt] = __builtin_amdgcn_mfma_f32_16x16x32_bf16(
          __builtin_bit_cast(bf16x8, afm1), __builtin_bit_cast(bf16x8, zf), acc[1][nt], 0, 0, 0);
    }
  }

  // bias + f32 out-bounce OVERLAID on the z1 slice (all zf reads precede these
  // writes in same-wave program order -> race-free), then coalesced epilogue.
  {
    float biasv[4];
    #pragma unroll
    for (int nt = 0; nt < 4; ++nt) biasv[nt] = bias[nt * 16 + lr];
    #pragma unroll
    for (int mt = 0; mt < 2; ++mt)
      #pragma unroll
      for (int nt = 0; nt < 4; ++nt)
        #pragma unroll
        for (int b = 0; b < 4; ++b) {
          int row = mt * 16 + hg * 4 + b;
          if (row < NE)
            *(float*)(&z1[swz(row, (nt * 16 + lr) * 4)]) = acc[mt][nt][b] + biasv[nt];
        }
  }
  const long long orow0 = (long long)g * NE;
  #pragma unroll
  for (int p = 0; p < 5; ++p) {
    int q = p * 64 + lane;
    if (q < NE * 16) {
      int r = q >> 4, c = q & 15;
      f32x4 v = *(const f32x4*)(&z1[swz(r, c * 16)]);
      *(f32x4*)(out + (orow0 + r) * CIN + c * 4) = v;
    }
  }
}

extern "C" void kernel_launch(void* const* d_in, const int* in_sizes, int n_in,
                              void* d_out, int out_size, void* d_ws, size_t ws_size,
                              hipStream_t stream) {
  const float* x    = (const float*)d_in[0];
  const float* ew   = (const float*)d_in[1];
  const float* Wrel = (const float*)d_in[2];
  const float* Wroot= (const float*)d_in[3];
  const float* bias = (const float*)d_in[4];
  float* out = (float*)d_out;
  unsigned char* ws = (unsigned char*)d_ws;   // needs 18432 B

  prep_kernel<<<5, 256, 0, stream>>>(ew, Wrel, Wroot, ws);

  const int ngraphs = (in_sizes[0] / CIN) / NE;   // 8192
  const int nblocks = ngraphs / 2;                // 4096 blocks, 1 graph/wave
  gconv_kernel<<<nblocks, 128, 0, stream>>>(x, bias, ws, out);
}

// Round 11
// 26.340 us; speedup vs baseline: 3.3541x; 1.0843x over previous
//
#include <hip/hip_runtime.h>

#define NE 19
#define CIN 64
#define Z1T_STRIDE 80          // bytes per Z1T row (32 bf16 of 40); 16B-aligned, 2-way banks = free
#define SLICE 5120             // per-graph slice: Z1T (64*80), then reused as f32 out-bounce (4864 B)
#define WS_AFRAG 16384         // ws: [0,16K) Wc B-frags; [16K,18K) A-mix A-frags

typedef float f32x4 __attribute__((ext_vector_type(4)));
typedef unsigned short u16x4 __attribute__((ext_vector_type(4)));
typedef unsigned short u16x8 __attribute__((ext_vector_type(8)));
typedef __bf16 bf16x8 __attribute__((ext_vector_type(8)));

__device__ __forceinline__ unsigned short f2bf(float f) {
  unsigned u = __builtin_bit_cast(unsigned, f);
  return (unsigned short)((u + 0x7FFFu + ((u >> 16) & 1u)) >> 16);
}
__device__ __forceinline__ int swz(int row, int byteoff) {
  return row * 256 + (byteoff ^ ((row & 7) << 4));
}

// K1 (5 blocks): pack Wc B-frags + softplus(A) A-frags (bf16) into workspace.
// B-frag fid = ((p*2+kt)*4+nt)*64+lane, p0=Wrel p1=Wroot.
__global__ void prep_kernel(const float* __restrict__ ew,
                            const float* __restrict__ Wrel,
                            const float* __restrict__ Wroot,
                            unsigned char* __restrict__ ws) {
  const int t = threadIdx.x, bid = blockIdx.x;
  if (bid < 4) {
    int fid = bid * 256 + t;
    int p = fid >> 9, kt = (fid >> 8) & 1, nt = (fid >> 6) & 3, lane = fid & 63;
    const float* Wsrc = p ? Wroot : Wrel;
    const float* q = Wsrc + (nt * 16 + (lane & 15)) * CIN + kt * 32 + (lane >> 4) * 8;
    u16x8 h;
    #pragma unroll
    for (int b = 0; b < 8; ++b) h[b] = f2bf(q[b]);
    *(u16x8*)(ws + fid * 16) = h;
  } else if (t < 128) {
    // A-mix A-frag: lane holds A[mt*16+(lane&15)][k=(lane>>4)*8+b], A[i][j]=sp(ew[j*19+i])
    int mt = t >> 6, lane = t & 63;
    int row = mt * 16 + (lane & 15);
    u16x8 h;
    #pragma unroll
    for (int b = 0; b < 8; ++b) {
      int k = (lane >> 4) * 8 + b;
      float v = 0.0f;
      if (row < NE && k < NE) {
        float z = ew[k * NE + row];
        v = fmaxf(z, 0.0f) + log1pf(expf(-fabsf(z)));
      }
      h[b] = f2bf(v);
    }
    *(u16x8*)(ws + WS_AFRAG + t * 16) = h;
  }
}

// K2: 2 graphs per wave (B-frags loaded once, shared), zero barriers, all
// compute in MFMA. out = A@(X@Wrel^T) + X@Wroot^T + bias
__global__ __launch_bounds__(128, 4) void gconv_kernel(
    const float* __restrict__ x, const float* __restrict__ bias,
    const unsigned char* __restrict__ ws, float* __restrict__ out)
{
  __shared__ __align__(16) unsigned char sl[4 * SLICE];  // 20480 B -> 8 blocks/CU

  const int t = threadIdx.x;
  const int lane = t & 63;
  const int wv = t >> 6;
  const int g0 = blockIdx.x * 4 + wv * 2;   // wave owns graphs g0, g0+1
  const int lr = lane & 15, hg = lane >> 4;
  const u16x8* fr = (const u16x8*)ws;
  unsigned char* slice[2] = { sl + (wv * 2) * SLICE, sl + (wv * 2 + 1) * SLICE };

  // ---- X A-frags for BOTH graphs (16 independent global loads issued up
  // front -> deep MLP; f32->bf16 on arrival). 16B/lane contiguous.
  u16x8 af[2][2][2];   // [graph][mt][kt]
  #pragma unroll
  for (int gi = 0; gi < 2; ++gi) {
    const float* xg = x + (long long)(g0 + gi) * NE * CIN;
    #pragma unroll
    for (int mt = 0; mt < 2; ++mt) {
      int rr = mt * 16 + lr; if (rr > NE - 1) rr = NE - 1;  // dup rows, writes guarded
      const float* xr = xg + rr * CIN + hg * 8;
      #pragma unroll
      for (int kt = 0; kt < 2; ++kt) {
        f32x4 a = *(const f32x4*)(xr + kt * 32);
        f32x4 b = *(const f32x4*)(xr + kt * 32 + 4);
        u16x8 h;
        h[0]=f2bf(a[0]); h[1]=f2bf(a[1]); h[2]=f2bf(a[2]); h[3]=f2bf(a[3]);
        h[4]=f2bf(b[0]); h[5]=f2bf(b[1]); h[6]=f2bf(b[2]); h[7]=f2bf(b[3]);
        af[gi][mt][kt] = h;
      }
    }
  }

  // ---- half 1 (both graphs share one B-frag load): Z1 = X @ Wrel^T
  {
    u16x8 bf1[8];   // [kt*4+nt]
    #pragma unroll
    for (int i = 0; i < 8; ++i) bf1[i] = fr[i * 64 + lane];
    #pragma unroll
    for (int gi = 0; gi < 2; ++gi) {
      f32x4 zacc[2][4];
      #pragma unroll
      for (int mt = 0; mt < 2; ++mt)
        #pragma unroll
        for (int nt = 0; nt < 4; ++nt) { zacc[mt][nt][0]=0.f; zacc[mt][nt][1]=0.f; zacc[mt][nt][2]=0.f; zacc[mt][nt][3]=0.f; }
      #pragma unroll
      for (int nt = 0; nt < 4; ++nt)
        #pragma unroll
        for (int mt = 0; mt < 2; ++mt) {
          zacc[mt][nt] = __builtin_amdgcn_mfma_f32_16x16x32_bf16(
              __builtin_bit_cast(bf16x8, af[gi][mt][0]), __builtin_bit_cast(bf16x8, bf1[nt]), zacc[mt][nt], 0, 0, 0);
          zacc[mt][nt] = __builtin_amdgcn_mfma_f32_16x16x32_bf16(
              __builtin_bit_cast(bf16x8, af[gi][mt][1]), __builtin_bit_cast(bf16x8, bf1[4 + nt]), zacc[mt][nt], 0, 0, 0);
        }
      // bounce Z1 -> Z1T[c][j] bf16 (j 19..31 zeroed), 8 ds_write_b64
      unsigned char* z1 = slice[gi];
      #pragma unroll
      for (int nt = 0; nt < 4; ++nt) {
        int c = nt * 16 + lr;
        u16x4 h0;
        #pragma unroll
        for (int b = 0; b < 4; ++b) h0[b] = f2bf(zacc[0][nt][b]);
        *(u16x4*)(z1 + c * Z1T_STRIDE + hg * 8) = h0;
        u16x4 h1;
        #pragma unroll
        for (int b = 0; b < 4; ++b) {
          int j = 16 + hg * 4 + b;
          h1[b] = (j < NE) ? f2bf(zacc[1][nt][b]) : (unsigned short)0;
        }
        *(u16x4*)(z1 + c * Z1T_STRIDE + 32 + hg * 8) = h1;
      }
    }
  }

  // ---- half 2 + mix + epilogue (B-frags + A-mix frags shared across graphs)
  {
    u16x8 bf2[8];
    #pragma unroll
    for (int i = 0; i < 8; ++i) bf2[i] = fr[(8 + i) * 64 + lane];
    u16x8 afm0 = fr[1024 + lane];
    u16x8 afm1 = fr[1088 + lane];
    float biasv[4];
    #pragma unroll
    for (int nt = 0; nt < 4; ++nt) biasv[nt] = bias[nt * 16 + lr];

    #pragma unroll
    for (int gi = 0; gi < 2; ++gi) {
      unsigned char* z1 = slice[gi];
      f32x4 acc[2][4];
      #pragma unroll
      for (int mt = 0; mt < 2; ++mt)
        #pragma unroll
        for (int nt = 0; nt < 4; ++nt) { acc[mt][nt][0]=0.f; acc[mt][nt][1]=0.f; acc[mt][nt][2]=0.f; acc[mt][nt][3]=0.f; }
      #pragma unroll
      for (int nt = 0; nt < 4; ++nt)
        #pragma unroll
        for (int mt = 0; mt < 2; ++mt) {
          acc[mt][nt] = __builtin_amdgcn_mfma_f32_16x16x32_bf16(
              __builtin_bit_cast(bf16x8, af[gi][mt][0]), __builtin_bit_cast(bf16x8, bf2[nt]), acc[mt][nt], 0, 0, 0);
          acc[mt][nt] = __builtin_amdgcn_mfma_f32_16x16x32_bf16(
              __builtin_bit_cast(bf16x8, af[gi][mt][1]), __builtin_bit_cast(bf16x8, bf2[4 + nt]), acc[mt][nt], 0, 0, 0);
        }
      // mix as MFMA: acc += A @ Z1
      #pragma unroll
      for (int nt = 0; nt < 4; ++nt) {
        u16x8 zf = *(const u16x8*)(z1 + (nt * 16 + lr) * Z1T_STRIDE + hg * 16);
        acc[0][nt] = __builtin_amdgcn_mfma_f32_16x16x32_bf16(
            __builtin_bit_cast(bf16x8, afm0), __builtin_bit_cast(bf16x8, zf), acc[0][nt], 0, 0, 0);
        acc[1][nt] = __builtin_amdgcn_mfma_f32_16x16x32_bf16(
            __builtin_bit_cast(bf16x8, afm1), __builtin_bit_cast(bf16x8, zf), acc[1][nt], 0, 0, 0);
      }
      // bias + f32 out-bounce OVERLAID on this graph's slice (all zf reads
      // precede these writes in same-wave program order -> race-free)
      #pragma unroll
      for (int mt = 0; mt < 2; ++mt)
        #pragma unroll
        for (int nt = 0; nt < 4; ++nt)
          #pragma unroll
          for (int b = 0; b < 4; ++b) {
            int row = mt * 16 + hg * 4 + b;
            if (row < NE)
              *(float*)(&z1[swz(row, (nt * 16 + lr) * 4)]) = acc[mt][nt][b] + biasv[nt];
          }
      // coalesced epilogue: 1KB contiguous per wave instruction
      const long long orow0 = (long long)(g0 + gi) * NE;
      #pragma unroll
      for (int p = 0; p < 5; ++p) {
        int q = p * 64 + lane;
        if (q < NE * 16) {
          int r = q >> 4, c = q & 15;
          f32x4 v = *(const f32x4*)(&z1[swz(r, c * 16)]);
          *(f32x4*)(out + (orow0 + r) * CIN + c * 4) = v;
        }
      }
    }
  }
}

extern "C" void kernel_launch(void* const* d_in, const int* in_sizes, int n_in,
                              void* d_out, int out_size, void* d_ws, size_t ws_size,
                              hipStream_t stream) {
  const float* x    = (const float*)d_in[0];
  const float* ew   = (const float*)d_in[1];
  const float* Wrel = (const float*)d_in[2];
  const float* Wroot= (const float*)d_in[3];
  const float* bias = (const float*)d_in[4];
  float* out = (float*)d_out;
  unsigned char* ws = (unsigned char*)d_ws;   // needs 18432 B

  prep_kernel<<<5, 256, 0, stream>>>(ew, Wrel, Wroot, ws);

  const int ngraphs = (in_sizes[0] / CIN) / NE;   // 8192
  const int nblocks = ngraphs / 4;                // 2048 blocks, 2 graphs/wave
  gconv_kernel<<<nblocks, 128, 0, stream>>>(x, bias, ws, out);
}